// Round 4
// baseline (59.938 us; speedup 1.0000x reference)
//
#include <hip/hip_runtime.h>
#include <math.h>

#define NFEAT  512
#define NHID   128
#define NCLASS 70
#define NIDX   10000
#define NBLK   625            // 625 blocks x 16 rows = 10000
#define BLKT   64             // one wave per block, fully autonomous

typedef float  f32x4  __attribute__((ext_vector_type(4)));
typedef __bf16 bf16x8 __attribute__((ext_vector_type(8)));

static __device__ __forceinline__ unsigned short f2bf(float f) {
    unsigned u = __builtin_bit_cast(unsigned, f);
    u += 0x7fffu + ((u >> 16) & 1u);
    return (unsigned short)(u >> 16);
}
static __device__ __forceinline__ float bf2f(unsigned short h) {
    unsigned u = ((unsigned)h) << 16;
    return __builtin_bit_cast(float, u);
}
static __device__ __forceinline__ bf16x8 pack8(float4 a, float4 b) {
    bf16x8 r;
    r[0] = (__bf16)a.x; r[1] = (__bf16)a.y; r[2] = (__bf16)a.z; r[3] = (__bf16)a.w;
    r[4] = (__bf16)b.x; r[5] = (__bf16)b.y; r[6] = (__bf16)b.z; r[7] = (__bf16)b.w;
    return r;
}
static __device__ __forceinline__ f32x4 MFMA(bf16x8 a, bf16x8 b, f32x4 c) {
    return __builtin_amdgcn_mfma_f32_16x16x32_bf16(a, b, c, 0, 0, 0);
}
// T2-style XOR swizzle on a [16][128]-bf16 tile (row stride 256 B)
static __device__ __forceinline__ int swz(int row, int offb) {
    return row * 256 + (offb ^ ((row & 7) << 4));
}

template<bool PRE>
static __device__ __forceinline__ bf16x8 bfrag(const void* p, size_t off) {
    if constexpr (PRE) {
        return *(const bf16x8*)((const unsigned short*)p + off);
    } else {
        const float4* q = (const float4*)((const float*)p + off);
        return pack8(q[0], q[1]);
    }
}

// ---- prep: all weights f32 -> bf16 into d_ws (same row-major order) ----
__global__ void prep_weights(const float* __restrict__ W0, const float* __restrict__ W1,
                             const float* __restrict__ G1, const float* __restrict__ G2,
                             const float* __restrict__ GT, const float* __restrict__ Wc,
                             unsigned short* __restrict__ ws) {
    int i4 = blockIdx.x * 256 + threadIdx.x;
    if (i4 >= 51392) return;
    const float* src; int base4;
    if      (i4 < 16384) { src = W0; base4 = 0; }
    else if (i4 < 32768) { src = W1; base4 = 16384; }
    else if (i4 < 36864) { src = G1; base4 = 32768; }
    else if (i4 < 40960) { src = G2; base4 = 36864; }
    else if (i4 < 49152) { src = GT; base4 = 40960; }
    else                 { src = Wc; base4 = 49152; }
    float4 v = ((const float4*)src)[i4 - base4];
    ushort4 o;
    o.x = f2bf(v.x); o.y = f2bf(v.y); o.z = f2bf(v.z); o.w = f2bf(v.w);
    ((ushort4*)ws)[i4] = o;
}

// Wave-autonomous kernel: each 64-thread block handles 16 output rows end-to-end.
// All matmuls in swapped form mfma(Wrows_frag, Xrows_frag) -> D[j, m]:
//   output col = m = lane&15 (invariant), output row j = (lane>>4)*4 + reg.
// Stage outputs bounce through wave-private swizzled LDS (8 B per jt-tile per lane).
template<bool PRE>
__global__ __launch_bounds__(BLKT, 3) void hyper_wave(
    const float* __restrict__ x, const float* __restrict__ sf,
    const int* __restrict__ idx,
    const float* __restrict__ W0, const float* __restrict__ W1,
    const float* __restrict__ G1, const float* __restrict__ G2,
    const float* __restrict__ GT, const float* __restrict__ Wc,
    const unsigned short* __restrict__ wsb,
    float* __restrict__ out)
{
    __shared__ __align__(16) unsigned short Hls[2][16][128];  // 8 KB relu hidden (swizzled)
    __shared__ __align__(16) unsigned short Gls[2][16][128];  // 8 KB gate pre-act; FIX aliases Gls[0]

    const void* W0p = PRE ? (const void*)wsb            : (const void*)W0;
    const void* W1p = PRE ? (const void*)(wsb + 65536)  : (const void*)W1;
    const void* G1p = PRE ? (const void*)(wsb + 131072) : (const void*)G1;
    const void* G2p = PRE ? (const void*)(wsb + 147456) : (const void*)G2;
    const void* GTp = PRE ? (const void*)(wsb + 163840) : (const void*)GT;
    const void* Wcp = PRE ? (const void*)(wsb + 196608) : (const void*)Wc;

    const int lane = threadIdx.x;        // 0..63
    const int ln = lane & 15, lg = lane >> 4;
    const int bid = blockIdx.x;

    char* hb = (char*)&Hls[0][0][0];
    char* gb = (char*)&Gls[0][0][0];
    char* fb = gb;                       // FIX aliases Gls[0] (dead after stage D MFMAs)

    const int rowA = idx[bid * 16 + ln]; // this lane's output row (4 lanes share)
    const float* xrow = x  + (size_t)rowA * NFEAT;
    const float* srow = sf + (size_t)rowA * NFEAT;

    const f32x4 zero4 = {0.f, 0.f, 0.f, 0.f};

    // ---- stage B: H[t] = relu(scl1 * X[t] @ W[t]^T); X read once from HBM ----
    #pragma unroll
    for (int t = 0; t < 2; ++t) {
        const float* src = t ? srow : xrow;
        const void* Wp = t ? W1p : W0p;
        f32x4 acc[8];
        #pragma unroll
        for (int jt = 0; jt < 8; ++jt) acc[jt] = zero4;
        float ss = 0.f;
        for (int kc = 0; kc < 16; ++kc) {
            const float4* q = (const float4*)(src + kc * 32 + lg * 8);
            float4 a = q[0], b = q[1];
            ss += a.x*a.x + a.y*a.y + a.z*a.z + a.w*a.w
                + b.x*b.x + b.y*b.y + b.z*b.z + b.w*b.w;
            bf16x8 xf = pack8(a, b);
            #pragma unroll
            for (int jt = 0; jt < 8; ++jt) {
                bf16x8 wf = bfrag<PRE>(Wp, (size_t)(jt * 16 + ln) * NFEAT + kc * 32 + lg * 8);
                acc[jt] = MFMA(wf, xf, acc[jt]);
            }
        }
        // row-ln sumsq: this lane covered cols == lg*8 (mod 32); reduce over lg lanes
        ss += __shfl_xor(ss, 16); ss += __shfl_xor(ss, 32);
        float scl = (ss > 0.f) ? (1.f / sqrtf(ss)) : 0.f;
        char* hd = hb + t * 4096;
        #pragma unroll
        for (int jt = 0; jt < 8; ++jt) {
            ushort4 p;
            p.x = f2bf(fmaxf(acc[jt][0] * scl, 0.f));
            p.y = f2bf(fmaxf(acc[jt][1] * scl, 0.f));
            p.z = f2bf(fmaxf(acc[jt][2] * scl, 0.f));
            p.w = f2bf(fmaxf(acc[jt][3] * scl, 0.f));
            *(ushort4*)(hd + swz(ln, jt * 32 + lg * 8)) = p;   // H[m=ln][j=jt*16+lg*4 ..+4]
        }
    }
    __syncthreads();   // 1-wave block: ~free; orders LDS write->read

    // ---- stage C: g12[t] = H[t] @ G{1,2}^T (pre-activation) ----
    #pragma unroll
    for (int t = 0; t < 2; ++t) {
        const void* Gp = t ? G2p : G1p;
        f32x4 acc[8];
        #pragma unroll
        for (int jt = 0; jt < 8; ++jt) acc[jt] = zero4;
        #pragma unroll
        for (int kc = 0; kc < 4; ++kc) {
            bf16x8 hf = *(const bf16x8*)(hb + t * 4096 + swz(ln, kc * 64 + lg * 16));
            #pragma unroll
            for (int jt = 0; jt < 8; ++jt) {
                bf16x8 gf = bfrag<PRE>(Gp, (size_t)(jt * 16 + ln) * NHID + kc * 32 + lg * 8);
                acc[jt] = MFMA(gf, hf, acc[jt]);
            }
        }
        char* gd = gb + t * 4096;
        #pragma unroll
        for (int jt = 0; jt < 8; ++jt) {
            ushort4 p;
            p.x = f2bf(acc[jt][0]); p.y = f2bf(acc[jt][1]);
            p.z = f2bf(acc[jt][2]); p.w = f2bf(acc[jt][3]);
            *(ushort4*)(gd + swz(ln, jt * 32 + lg * 8)) = p;
        }
    }
    __syncthreads();

    // ---- stage D: u = [g1,g2] @ GT^T; gate = sigmoid(u); fix = (1-g)H0 + gH1 ----
    float scl2;
    {
        f32x4 acc[8];
        #pragma unroll
        for (int jt = 0; jt < 8; ++jt) acc[jt] = zero4;
        #pragma unroll
        for (int kc = 0; kc < 8; ++kc) {
            bf16x8 cf = *(const bf16x8*)(gb + (kc >> 2) * 4096 + swz(ln, (kc & 3) * 64 + lg * 16));
            #pragma unroll
            for (int jt = 0; jt < 8; ++jt) {
                bf16x8 tf = bfrag<PRE>(GTp, (size_t)(jt * 16 + ln) * (2 * NHID) + kc * 32 + lg * 8);
                acc[jt] = MFMA(tf, cf, acc[jt]);
            }
        }
        __syncthreads();   // all Gls reads retired before FIX overwrite
        float fsq = 0.f;
        #pragma unroll
        for (int jt = 0; jt < 8; ++jt) {
            ushort4 h0 = *(const ushort4*)(hb +        swz(ln, jt * 32 + lg * 8));
            ushort4 h1 = *(const ushort4*)(hb + 4096 + swz(ln, jt * 32 + lg * 8));
            float f0, f1, f2, f3;
            {
                float g;
                g = 1.f / (1.f + __expf(-acc[jt][0])); f0 = (1.f - g) * bf2f(h0.x) + g * bf2f(h1.x);
                g = 1.f / (1.f + __expf(-acc[jt][1])); f1 = (1.f - g) * bf2f(h0.y) + g * bf2f(h1.y);
                g = 1.f / (1.f + __expf(-acc[jt][2])); f2 = (1.f - g) * bf2f(h0.z) + g * bf2f(h1.z);
                g = 1.f / (1.f + __expf(-acc[jt][3])); f3 = (1.f - g) * bf2f(h0.w) + g * bf2f(h1.w);
            }
            fsq += f0*f0 + f1*f1 + f2*f2 + f3*f3;
            ushort4 p;
            p.x = f2bf(f0); p.y = f2bf(f1); p.z = f2bf(f2); p.w = f2bf(f3);
            *(ushort4*)(fb + swz(ln, jt * 32 + lg * 8)) = p;
        }
        fsq += __shfl_xor(fsq, 16); fsq += __shfl_xor(fsq, 32);
        scl2 = (fsq > 0.f) ? (1.f / sqrtf(fsq)) : 0.f;
    }
    __syncthreads();

    // ---- stage E: logits = relu(scl2 * fix @ Wc^T); log_softmax; store ----
    {
        bf16x8 zf;
        #pragma unroll
        for (int j = 0; j < 8; ++j) zf[j] = (__bf16)0.f;
        f32x4 acc[5];
        #pragma unroll
        for (int jt = 0; jt < 5; ++jt) acc[jt] = zero4;
        #pragma unroll
        for (int kc = 0; kc < 4; ++kc) {
            bf16x8 ff = *(const bf16x8*)(fb + swz(ln, kc * 64 + lg * 16));
            #pragma unroll
            for (int jt = 0; jt < 5; ++jt) {
                int c = jt * 16 + ln;      // Wc row to load
                bf16x8 wf = (c < NCLASS) ? bfrag<PRE>(Wcp, (size_t)c * NHID + kc * 32 + lg * 8) : zf;
                acc[jt] = MFMA(wf, ff, acc[jt]);
            }
        }
        // lane holds logits[c = jt*16 + lg*4 + r][m = ln]
        f32x4 lv[5];
        float mx = -1e30f;
        #pragma unroll
        for (int jt = 0; jt < 5; ++jt)
            #pragma unroll
            for (int r = 0; r < 4; ++r) {
                int c = jt * 16 + lg * 4 + r;
                float v = (c < NCLASS) ? fmaxf(acc[jt][r] * scl2, 0.f) : -1e30f;
                lv[jt][r] = v;
                mx = fmaxf(mx, v);
            }
        mx = fmaxf(mx, __shfl_xor(mx, 16)); mx = fmaxf(mx, __shfl_xor(mx, 32));
        float se = 0.f;
        #pragma unroll
        for (int jt = 0; jt < 5; ++jt)
            #pragma unroll
            for (int r = 0; r < 4; ++r) se += __expf(lv[jt][r] - mx);  // exp(-1e30)=0
        se += __shfl_xor(se, 16); se += __shfl_xor(se, 32);
        float lz = mx + __logf(se);

        float* ob = out + ((size_t)bid * 16 + ln) * NCLASS;
        #pragma unroll
        for (int jt = 0; jt < 5; ++jt) {
            int c0 = jt * 16 + lg * 4;
            if (c0 + 1 < NCLASS) {
                float2 s0 = {lv[jt][0] - lz, lv[jt][1] - lz};
                *(float2*)(ob + c0) = s0;
            }
            if (c0 + 3 < NCLASS) {
                float2 s1 = {lv[jt][2] - lz, lv[jt][3] - lz};
                *(float2*)(ob + c0 + 2) = s1;
            }
        }
    }
}

extern "C" void kernel_launch(void* const* d_in, const int* in_sizes, int n_in,
                              void* d_out, int out_size, void* d_ws, size_t ws_size,
                              hipStream_t stream)
{
    const float* x   = (const float*)d_in[0];
    const float* sf  = (const float*)d_in[1];
    const int*   idx = (const int*)d_in[2];
    const float* W0  = (const float*)d_in[3];
    const float* W1  = (const float*)d_in[4];
    const float* G1  = (const float*)d_in[5];
    const float* G2  = (const float*)d_in[6];
    const float* GT  = (const float*)d_in[7];
    const float* Wc  = (const float*)d_in[8];
    float* out = (float*)d_out;

    const size_t need = 205568ull * 2;   // all weights as bf16
    if (ws_size >= need) {
        unsigned short* ws = (unsigned short*)d_ws;
        prep_weights<<<dim3(201), dim3(256), 0, stream>>>(W0, W1, G1, G2, GT, Wc, ws);
        hyper_wave<true><<<dim3(NBLK), dim3(BLKT), 0, stream>>>(
            x, sf, idx, W0, W1, G1, G2, GT, Wc, ws, out);
    } else {
        hyper_wave<false><<<dim3(NBLK), dim3(BLKT), 0, stream>>>(
            x, sf, idx, W0, W1, G1, G2, GT, Wc, nullptr, out);
    }
}

// Round 5
// 55.082 us; speedup vs baseline: 1.0882x; 1.0882x over previous
//
#include <hip/hip_runtime.h>
#include <math.h>

#define NFEAT  512
#define NHID   128
#define NCLASS 70
#define NIDX   10000
#define BM     16
#define NTHREADS 512
#define NBLK   (NIDX / BM)            // 625
#define GATHER_BLKS 2500              // 4 rows x 2 tensors per block
#define W4TOT  51392                  // total float4 slots across all weights
#define PREP_BLKS ((W4TOT + 255) / 256)   // 201
#define XELEMS (2u * NIDX * NFEAT)    // 10,240,000 ushort
#define WOFF   XELEMS
#define WS_NEED ((size_t)(XELEMS + 205568) * 2)   // ~20.9 MB

typedef float  f32x4  __attribute__((ext_vector_type(4)));
typedef __bf16 bf16x8 __attribute__((ext_vector_type(8)));

static __device__ __forceinline__ unsigned short f2bf(float f) {
    unsigned u = __builtin_bit_cast(unsigned, f);
    u += 0x7fffu + ((u >> 16) & 1u);
    return (unsigned short)(u >> 16);
}
static __device__ __forceinline__ float bf2f(unsigned short h) {
    unsigned u = ((unsigned)h) << 16;
    return __builtin_bit_cast(float, u);
}
static __device__ __forceinline__ bf16x8 pack8(float4 a, float4 b) {
    bf16x8 r;
    r[0] = (__bf16)a.x; r[1] = (__bf16)a.y; r[2] = (__bf16)a.z; r[3] = (__bf16)a.w;
    r[4] = (__bf16)b.x; r[5] = (__bf16)b.y; r[6] = (__bf16)b.z; r[7] = (__bf16)b.w;
    return r;
}
static __device__ __forceinline__ f32x4 MFMA(bf16x8 a, bf16x8 b, f32x4 c) {
    return __builtin_amdgcn_mfma_f32_16x16x32_bf16(a, b, c, 0, 0, 0);
}
static __device__ __forceinline__ bf16x8 ldsAx(const unsigned short* base, int row, int colb, int rstride) {
    return *(const bf16x8*)((const char*)base + row * rstride + (colb ^ ((row & 7) << 4)));
}
static __device__ __forceinline__ void ldsW1(unsigned short* base, int row, int col, unsigned short v) {
    *(unsigned short*)((char*)base + row * 256 + ((col * 2) ^ ((row & 7) << 4))) = v;
}
static __device__ __forceinline__ float ldsR1(const unsigned short* base, int row, int col) {
    return bf2f(*(const unsigned short*)((const char*)base + row * 256 + ((col * 2) ^ ((row & 7) << 4))));
}
static __device__ __forceinline__ void gload16(const void* g, void* l) {
    __builtin_amdgcn_global_load_lds(
        (const __attribute__((address_space(1))) unsigned int*)g,
        (__attribute__((address_space(3))) unsigned int*)l, 16, 0, 0);
}
static __device__ __forceinline__ ushort4 pk4(float4 a, float s) {
    ushort4 o;
    o.x = f2bf(a.x * s); o.y = f2bf(a.y * s); o.z = f2bf(a.z * s); o.w = f2bf(a.w * s);
    return o;
}

// ---- kernel 1: gather+normalize X rows to dense bf16 in ws; prep weights to bf16 ----
__global__ __launch_bounds__(256) void stage_inputs(
    const float* __restrict__ x, const float* __restrict__ sf,
    const int* __restrict__ idx,
    const float* __restrict__ W0, const float* __restrict__ W1,
    const float* __restrict__ G1, const float* __restrict__ G2,
    const float* __restrict__ GT, const float* __restrict__ Wc,
    unsigned short* __restrict__ ws)
{
    const int b = blockIdx.x, tid = threadIdx.x;
    if (b >= GATHER_BLKS) {
        // weight prep: f32 -> bf16, same row-major packing
        int i4 = (b - GATHER_BLKS) * 256 + tid;
        if (i4 >= W4TOT) return;
        const float* src; int base4;
        if      (i4 < 16384) { src = W0; base4 = 0; }
        else if (i4 < 32768) { src = W1; base4 = 16384; }
        else if (i4 < 36864) { src = G1; base4 = 32768; }
        else if (i4 < 40960) { src = G2; base4 = 36864; }
        else if (i4 < 49152) { src = GT; base4 = 40960; }
        else                 { src = Wc; base4 = 49152; }
        float4 v = ((const float4*)src)[i4 - base4];
        ((ushort4*)(ws + WOFF))[i4] = pk4(v, 1.f);
        return;
    }
    // gather: block handles 4 output rows x 2 tensors; 32 lanes per (t,row)
    const int p = tid >> 5, l = tid & 31;
    const int t = p >> 2, rr = p & 3;
    const int i = b * 4 + rr;                    // 2500*4 == 10000 exact
    const int row = idx[i];
    const float4* src = (const float4*)((t ? sf : x) + (size_t)row * NFEAT);
    float4 v0 = src[l], v1 = src[l + 32], v2 = src[l + 64], v3 = src[l + 96];
    float ss = v0.x*v0.x + v0.y*v0.y + v0.z*v0.z + v0.w*v0.w
             + v1.x*v1.x + v1.y*v1.y + v1.z*v1.z + v1.w*v1.w
             + v2.x*v2.x + v2.y*v2.y + v2.z*v2.z + v2.w*v2.w
             + v3.x*v3.x + v3.y*v3.y + v3.z*v3.z + v3.w*v3.w;
    #pragma unroll
    for (int d = 1; d < 32; d <<= 1) ss += __shfl_xor(ss, d, 32);
    float scl = (ss > 0.f) ? (1.f / sqrtf(ss)) : 0.f;   // L2-norm folded into stored X
    ushort4* dst = (ushort4*)(ws + ((size_t)t * NIDX + i) * NFEAT);
    dst[l]      = pk4(v0, scl);
    dst[l + 32] = pk4(v1, scl);
    dst[l + 64] = pk4(v2, scl);
    dst[l + 96] = pk4(v3, scl);
}

// ---- kernel 2: dense main compute (X pre-normalized bf16 in ws) ----
__global__ __launch_bounds__(NTHREADS) void hyper_main(
    const unsigned short* __restrict__ ws, float* __restrict__ out)
{
    __shared__ __align__(16) unsigned short Xbuf[2][BM][NFEAT]; // 32 KB
    __shared__ __align__(16) unsigned short Hbuf[2][BM][NHID];  // 8 KB
    __shared__ float scl2[BM];

    unsigned short* G12 = &Xbuf[0][0][0];            // [2][16][128] aliases X (dead after B)
    unsigned short* FIX = &Xbuf[0][0][0] + 4096;     // [16][128]
    float*          LOG = (float*)(&Xbuf[0][0][0] + 6144); // [16][80]

    const unsigned short* Wb  = ws + WOFF;
    const unsigned short* W0p = Wb;
    const unsigned short* W1p = Wb + 65536;
    const unsigned short* G1p = Wb + 131072;
    const unsigned short* G2p = Wb + 147456;
    const unsigned short* GTp = Wb + 163840;
    const unsigned short* Wcp = Wb + 196608;

    const int tid  = threadIdx.x;
    const int bid  = blockIdx.x;
    const int w    = tid >> 6;
    const int lane = tid & 63;
    const int ln   = lane & 15, lg = lane >> 4;

    // ---- stage X into LDS: async 16B direct-to-LDS, pre-swizzled global source ----
    // wave w stages rows p = 4w..4w+3 (p = t*16+m); LDS linear, read-side XOR matches.
    #pragma unroll
    for (int j = 0; j < 4; ++j) {
        int p = w * 4 + j;
        int t = p >> 4, m = p & 15;
        const char* g = (const char*)(ws + ((size_t)t * NIDX + (size_t)bid * BM + m) * NFEAT)
                      + ((lane * 16) ^ ((m & 7) << 4));
        char* l = (char*)&Xbuf[0][0][0] + t * 16384 + m * 1024;
        gload16(g, l);
    }
    __syncthreads();

    const int tB = w >> 2, nq = w & 3;
    const f32x4 zero4 = {0.f, 0.f, 0.f, 0.f};

    // ---- stage B: H[t] = relu(X'[t] @ W[t]^T)  (norm already folded into X') ----
    {
        const unsigned short* Wp = tB ? W1p : W0p;
        f32x4 accB[2] = {zero4, zero4};
        const unsigned short* Xb = (const unsigned short*)((const char*)&Xbuf[0][0][0] + tB * 16384);
        #pragma unroll
        for (int kc = 0; kc < 16; ++kc) {
            bf16x8 a = ldsAx(Xb, ln, kc * 64 + lg * 16, 1024);
            #pragma unroll
            for (int nt = 0; nt < 2; ++nt) {
                int n = nq * 32 + nt * 16 + ln;
                bf16x8 b = *(const bf16x8*)(Wp + (size_t)n * NFEAT + kc * 32 + lg * 8);
                accB[nt] = MFMA(a, b, accB[nt]);
            }
        }
        unsigned short* Hb = &Hbuf[tB][0][0];
        #pragma unroll
        for (int nt = 0; nt < 2; ++nt)
            #pragma unroll
            for (int rg = 0; rg < 4; ++rg) {
                int m = lg * 4 + rg;
                ldsW1(Hb, m, nq * 32 + nt * 16 + ln, f2bf(fmaxf(accB[nt][rg], 0.f)));
            }
    }
    __syncthreads();

    // ---- stage C: gate1/gate2 = H[t] @ G{1,2}^T ----
    {
        const unsigned short* Gp = tB ? G2p : G1p;
        const unsigned short* Hs = &Hbuf[tB][0][0];
        f32x4 accC[2] = {zero4, zero4};
        #pragma unroll
        for (int kc = 0; kc < 4; ++kc) {
            bf16x8 a = ldsAx(Hs, ln, kc * 64 + lg * 16, 256);
            #pragma unroll
            for (int nt = 0; nt < 2; ++nt) {
                int n = nq * 32 + nt * 16 + ln;
                bf16x8 b = *(const bf16x8*)(Gp + (size_t)n * NHID + kc * 32 + lg * 8);
                accC[nt] = MFMA(a, b, accC[nt]);
            }
        }
        unsigned short* Gd = G12 + tB * 2048;
        #pragma unroll
        for (int nt = 0; nt < 2; ++nt)
            #pragma unroll
            for (int rg = 0; rg < 4; ++rg) {
                int m = lg * 4 + rg;
                ldsW1(Gd, m, nq * 32 + nt * 16 + ln, f2bf(accC[nt][rg]));
            }
    }
    __syncthreads();

    // ---- stage D: gate = sigmoid([g1,g2] @ GT^T); fix = (1-g)H0 + gH1 ----
    {
        f32x4 accD = zero4;
        const int n = w * 16 + ln;
        #pragma unroll
        for (int kc = 0; kc < 8; ++kc) {
            const unsigned short* As = G12 + (kc >> 2) * 2048;
            bf16x8 a = ldsAx(As, ln, (kc & 3) * 64 + lg * 16, 256);
            bf16x8 b = *(const bf16x8*)(GTp + (size_t)n * (2 * NHID) + kc * 32 + lg * 8);
            accD = MFMA(a, b, accD);
        }
        #pragma unroll
        for (int rg = 0; rg < 4; ++rg) {
            int m = lg * 4 + rg;
            float g  = 1.f / (1.f + __expf(-accD[rg]));
            float h0 = ldsR1(&Hbuf[0][0][0], m, n);
            float h1 = ldsR1(&Hbuf[1][0][0], m, n);
            ldsW1(FIX, m, n, f2bf((1.f - g) * h0 + g * h1));
        }
    }
    __syncthreads();

    // ---- fix_inner row norms -> scl2 ----
    if (tid < 256) {
        int r = tid >> 4, sl = tid & 15;
        bf16x8 v = ldsAx(FIX, r, sl * 16, 256);
        float ss = 0.f;
        #pragma unroll
        for (int j = 0; j < 8; ++j) { float f = (float)v[j]; ss += f * f; }
        ss += __shfl_xor(ss, 1); ss += __shfl_xor(ss, 2);
        ss += __shfl_xor(ss, 4); ss += __shfl_xor(ss, 8);
        if (sl == 0) scl2[r] = (ss > 0.f) ? (1.f / sqrtf(ss)) : 0.f;
    }
    __syncthreads();

    // ---- stage E: logits = relu(scl2 * fix @ Wc^T) ----
    if (w < 5) {
        const int cc = w * 16 + ln;
        bf16x8 bfz;
        #pragma unroll
        for (int j = 0; j < 8; ++j) bfz[j] = (__bf16)0.f;
        f32x4 accE = zero4;
        #pragma unroll
        for (int kc = 0; kc < 4; ++kc) {
            bf16x8 a = ldsAx(FIX, ln, kc * 64 + lg * 16, 256);
            bf16x8 b = (cc < NCLASS) ? *(const bf16x8*)(Wcp + (size_t)cc * NHID + kc * 32 + lg * 8) : bfz;
            accE = MFMA(a, b, accE);
        }
        #pragma unroll
        for (int rg = 0; rg < 4; ++rg) {
            int m = lg * 4 + rg;
            float v = fmaxf(accE[rg] * scl2[m], 0.f);
            LOG[m * 80 + cc] = (cc < NCLASS) ? v : -1e30f;
        }
    }
    __syncthreads();

    // ---- log_softmax + store ----
    {
        const int r = tid >> 5, l32 = tid & 31;
        float v0 = LOG[r * 80 + l32];
        float v1 = LOG[r * 80 + 32 + l32];
        float v2 = (l32 < 16) ? LOG[r * 80 + 64 + l32] : -1e30f;
        float mx = fmaxf(fmaxf(v0, v1), v2);
        #pragma unroll
        for (int d = 1; d < 32; d <<= 1) mx = fmaxf(mx, __shfl_xor(mx, d, 32));
        float se = __expf(v0 - mx) + __expf(v1 - mx) + ((l32 < 16) ? __expf(v2 - mx) : 0.f);
        #pragma unroll
        for (int d = 1; d < 32; d <<= 1) se += __shfl_xor(se, d, 32);
        float lz = mx + __logf(se);
        size_t orow = (size_t)bid * BM + r;
        out[orow * NCLASS + l32] = v0 - lz;
        if (l32 + 32 < NCLASS) out[orow * NCLASS + 32 + l32] = v1 - lz;
        if (l32 + 64 < NCLASS) out[orow * NCLASS + 64 + l32] = v2 - lz;
    }
}

// ---- fallback: round-3 fused kernel, f32 weights direct (used only if ws too small) ----
static __device__ __forceinline__ bf16x8 bfragF(const float* p, size_t off) {
    const float4* q = (const float4*)(p + off);
    return pack8(q[0], q[1]);
}
__global__ __launch_bounds__(NTHREADS) void hyper_fb(
    const float* __restrict__ x, const float* __restrict__ sf,
    const int* __restrict__ idx,
    const float* __restrict__ W0, const float* __restrict__ W1,
    const float* __restrict__ G1, const float* __restrict__ G2,
    const float* __restrict__ GT, const float* __restrict__ Wc,
    float* __restrict__ out)
{
    __shared__ __align__(16) unsigned short Xbuf[2][BM][NFEAT];
    __shared__ __align__(16) unsigned short Hbuf[2][BM][NHID];
    __shared__ float scl1[32];
    __shared__ float scl2[BM];
    __shared__ int   rowsL[BM];
    unsigned short* G12 = &Xbuf[0][0][0];
    unsigned short* FIX = &Xbuf[0][0][0] + 4096;
    float*          LOG = (float*)(&Xbuf[0][0][0] + 6144);

    const int tid = threadIdx.x, bid = blockIdx.x;
    const int w = tid >> 6, lane = tid & 63;
    const int ln = lane & 15, lg = lane >> 4;

    if (tid < BM) rowsL[tid] = idx[bid * BM + tid];
    __syncthreads();
    float part[4];
    {
        char* xb = (char*)&Xbuf[0][0][0];
        #pragma unroll
        for (int i = 0; i < 4; ++i) {
            int s = tid + i * NTHREADS;
            int r = s >> 6, sl = s & 63;
            int t = r >> 4, m = r & 15;
            const float4* q = (const float4*)((t ? sf : x) + (size_t)rowsL[m] * NFEAT + sl * 8);
            float4 a = q[0], b = q[1];
            part[i] = a.x*a.x + a.y*a.y + a.z*a.z + a.w*a.w
                    + b.x*b.x + b.y*b.y + b.z*b.z + b.w*b.w;
            int soff = t * 16384 + m * 1024 + ((sl * 16) ^ ((m & 7) << 4));
            *(bf16x8*)(xb + soff) = pack8(a, b);
        }
        #pragma unroll
        for (int i = 0; i < 4; ++i) {
            float s = part[i];
            #pragma unroll
            for (int d = 1; d < 64; d <<= 1) s += __shfl_xor(s, d);
            if (lane == 0) scl1[w + 8 * i] = (s > 0.f) ? (1.f / sqrtf(s)) : 0.f;
        }
    }
    __syncthreads();
    const int tB = w >> 2, nq = w & 3;
    const f32x4 zero4 = {0.f, 0.f, 0.f, 0.f};
    {
        const float* Wp = tB ? W1 : W0;
        f32x4 accB[2] = {zero4, zero4};
        const unsigned short* Xb = (const unsigned short*)((const char*)&Xbuf[0][0][0] + tB * 16384);
        #pragma unroll
        for (int kc = 0; kc < 16; ++kc) {
            bf16x8 a = ldsAx(Xb, ln, kc * 64 + lg * 16, 1024);
            #pragma unroll
            for (int nt = 0; nt < 2; ++nt) {
                int n = nq * 32 + nt * 16 + ln;
                bf16x8 b = bfragF(Wp, (size_t)n * NFEAT + kc * 32 + lg * 8);
                accB[nt] = MFMA(a, b, accB[nt]);
            }
        }
        unsigned short* Hb = &Hbuf[tB][0][0];
        #pragma unroll
        for (int nt = 0; nt < 2; ++nt)
            #pragma unroll
            for (int rg = 0; rg < 4; ++rg) {
                int m = lg * 4 + rg;
                ldsW1(Hb, m, nq * 32 + nt * 16 + ln, f2bf(fmaxf(accB[nt][rg] * scl1[tB * 16 + m], 0.f)));
            }
    }
    __syncthreads();
    {
        const float* Gp = tB ? G2 : G1;
        const unsigned short* Hs = &Hbuf[tB][0][0];
        f32x4 accC[2] = {zero4, zero4};
        #pragma unroll
        for (int kc = 0; kc < 4; ++kc) {
            bf16x8 a = ldsAx(Hs, ln, kc * 64 + lg * 16, 256);
            #pragma unroll
            for (int nt = 0; nt < 2; ++nt) {
                int n = nq * 32 + nt * 16 + ln;
                bf16x8 b = bfragF(Gp, (size_t)n * NHID + kc * 32 + lg * 8);
                accC[nt] = MFMA(a, b, accC[nt]);
            }
        }
        unsigned short* Gd = G12 + tB * 2048;
        #pragma unroll
        for (int nt = 0; nt < 2; ++nt)
            #pragma unroll
            for (int rg = 0; rg < 4; ++rg) {
                int m = lg * 4 + rg;
                ldsW1(Gd, m, nq * 32 + nt * 16 + ln, f2bf(accC[nt][rg]));
            }
    }
    __syncthreads();
    {
        f32x4 accD = zero4;
        const int n = w * 16 + ln;
        #pragma unroll
        for (int kc = 0; kc < 8; ++kc) {
            const unsigned short* As = G12 + (kc >> 2) * 2048;
            bf16x8 a = ldsAx(As, ln, (kc & 3) * 64 + lg * 16, 256);
            bf16x8 b = bfragF(GT, (size_t)n * (2 * NHID) + kc * 32 + lg * 8);
            accD = MFMA(a, b, accD);
        }
        #pragma unroll
        for (int rg = 0; rg < 4; ++rg) {
            int m = lg * 4 + rg;
            float g  = 1.f / (1.f + __expf(-accD[rg]));
            float h0 = ldsR1(&Hbuf[0][0][0], m, n);
            float h1 = ldsR1(&Hbuf[1][0][0], m, n);
            ldsW1(FIX, m, n, f2bf((1.f - g) * h0 + g * h1));
        }
    }
    __syncthreads();
    if (tid < 256) {
        int r = tid >> 4, sl = tid & 15;
        bf16x8 v = ldsAx(FIX, r, sl * 16, 256);
        float ss = 0.f;
        #pragma unroll
        for (int j = 0; j < 8; ++j) { float f = (float)v[j]; ss += f * f; }
        ss += __shfl_xor(ss, 1); ss += __shfl_xor(ss, 2);
        ss += __shfl_xor(ss, 4); ss += __shfl_xor(ss, 8);
        if (sl == 0) scl2[r] = (ss > 0.f) ? (1.f / sqrtf(ss)) : 0.f;
    }
    __syncthreads();
    if (w < 5) {
        const int cc = w * 16 + ln;
        bf16x8 bfz;
        #pragma unroll
        for (int j = 0; j < 8; ++j) bfz[j] = (__bf16)0.f;
        f32x4 accE = zero4;
        #pragma unroll
        for (int kc = 0; kc < 4; ++kc) {
            bf16x8 a = ldsAx(FIX, ln, kc * 64 + lg * 16, 256);
            bf16x8 b = (cc < NCLASS) ? bfragF(Wc, (size_t)cc * NHID + kc * 32 + lg * 8) : bfz;
            accE = MFMA(a, b, accE);
        }
        #pragma unroll
        for (int rg = 0; rg < 4; ++rg) {
            int m = lg * 4 + rg;
            float v = fmaxf(accE[rg] * scl2[m], 0.f);
            LOG[m * 80 + cc] = (cc < NCLASS) ? v : -1e30f;
        }
    }
    __syncthreads();
    {
        const int r = tid >> 5, l32 = tid & 31;
        float v0 = LOG[r * 80 + l32];
        float v1 = LOG[r * 80 + 32 + l32];
        float v2 = (l32 < 16) ? LOG[r * 80 + 64 + l32] : -1e30f;
        float mx = fmaxf(fmaxf(v0, v1), v2);
        #pragma unroll
        for (int d = 1; d < 32; d <<= 1) mx = fmaxf(mx, __shfl_xor(mx, d, 32));
        float se = __expf(v0 - mx) + __expf(v1 - mx) + ((l32 < 16) ? __expf(v2 - mx) : 0.f);
        #pragma unroll
        for (int d = 1; d < 32; d <<= 1) se += __shfl_xor(se, d, 32);
        float lz = mx + __logf(se);
        size_t orow = (size_t)bid * BM + r;
        out[orow * NCLASS + l32] = v0 - lz;
        if (l32 + 32 < NCLASS) out[orow * NCLASS + 32 + l32] = v1 - lz;
        if (l32 + 64 < NCLASS) out[orow * NCLASS + 64 + l32] = v2 - lz;
    }
}

extern "C" void kernel_launch(void* const* d_in, const int* in_sizes, int n_in,
                              void* d_out, int out_size, void* d_ws, size_t ws_size,
                              hipStream_t stream)
{
    const float* x   = (const float*)d_in[0];
    const float* sf  = (const float*)d_in[1];
    const int*   idx = (const int*)d_in[2];
    const float* W0  = (const float*)d_in[3];
    const float* W1  = (const float*)d_in[4];
    const float* G1  = (const float*)d_in[5];
    const float* G2  = (const float*)d_in[6];
    const float* GT  = (const float*)d_in[7];
    const float* Wc  = (const float*)d_in[8];
    float* out = (float*)d_out;

    if (ws_size >= WS_NEED) {
        unsigned short* ws = (unsigned short*)d_ws;
        stage_inputs<<<dim3(GATHER_BLKS + PREP_BLKS), dim3(256), 0, stream>>>(
            x, sf, idx, W0, W1, G1, G2, GT, Wc, ws);
        hyper_main<<<dim3(NBLK), dim3(NTHREADS), 0, stream>>>(ws, out);
    } else {
        hyper_fb<<<dim3(NBLK), dim3(NTHREADS), 0, stream>>>(
            x, sf, idx, W0, W1, G1, G2, GT, Wc, out);
    }
}

// Round 6
// 51.045 us; speedup vs baseline: 1.1742x; 1.0791x over previous
//
#include <hip/hip_runtime.h>
#include <math.h>

#define NFEAT  512
#define NHID   128
#define NCLASS 70
#define NIDX   10000
#define BM     16
#define NTHREADS 512
#define NBLK   (NIDX / BM)            // 625
#define W4TOT  51392
#define PREP_BLKS ((W4TOT + 255) / 256)
#define WS_NEED ((size_t)205568 * 2)

typedef float  f32x4  __attribute__((ext_vector_type(4)));
typedef __bf16 bf16x8 __attribute__((ext_vector_type(8)));

static __device__ __forceinline__ unsigned short f2bf(float f) {
    unsigned u = __builtin_bit_cast(unsigned, f);
    u += 0x7fffu + ((u >> 16) & 1u);
    return (unsigned short)(u >> 16);
}
static __device__ __forceinline__ float bf2f(unsigned short h) {
    unsigned u = ((unsigned)h) << 16;
    return __builtin_bit_cast(float, u);
}
static __device__ __forceinline__ bf16x8 pack8(float4 a, float4 b) {
    bf16x8 r;
    r[0] = (__bf16)a.x; r[1] = (__bf16)a.y; r[2] = (__bf16)a.z; r[3] = (__bf16)a.w;
    r[4] = (__bf16)b.x; r[5] = (__bf16)b.y; r[6] = (__bf16)b.z; r[7] = (__bf16)b.w;
    return r;
}
static __device__ __forceinline__ f32x4 MFMA(bf16x8 a, bf16x8 b, f32x4 c) {
    return __builtin_amdgcn_mfma_f32_16x16x32_bf16(a, b, c, 0, 0, 0);
}
static __device__ __forceinline__ bf16x8 ldsAx(const unsigned short* base, int row, int colb, int rstride) {
    return *(const bf16x8*)((const char*)base + row * rstride + (colb ^ ((row & 7) << 4)));
}
static __device__ __forceinline__ void ldsW1(unsigned short* base, int row, int col, unsigned short v) {
    *(unsigned short*)((char*)base + row * 256 + ((col * 2) ^ ((row & 7) << 4))) = v;
}
static __device__ __forceinline__ float ldsR1(const unsigned short* base, int row, int col) {
    return bf2f(*(const unsigned short*)((const char*)base + row * 256 + ((col * 2) ^ ((row & 7) << 4))));
}
static __device__ __forceinline__ bf16x8 pack8s(float4 a, float4 b, float s) {
    bf16x8 r;
    r[0] = (__bf16)(a.x * s); r[1] = (__bf16)(a.y * s); r[2] = (__bf16)(a.z * s); r[3] = (__bf16)(a.w * s);
    r[4] = (__bf16)(b.x * s); r[5] = (__bf16)(b.y * s); r[6] = (__bf16)(b.z * s); r[7] = (__bf16)(b.w * s);
    return r;
}

// ---- prep: all weights f32 -> bf16 into d_ws ----
__global__ void prep_weights(const float* __restrict__ W0, const float* __restrict__ W1,
                             const float* __restrict__ G1, const float* __restrict__ G2,
                             const float* __restrict__ GT, const float* __restrict__ Wc,
                             unsigned short* __restrict__ ws) {
    int i4 = blockIdx.x * 256 + threadIdx.x;
    if (i4 >= W4TOT) return;
    const float* src; int base4;
    if      (i4 < 16384) { src = W0; base4 = 0; }
    else if (i4 < 32768) { src = W1; base4 = 16384; }
    else if (i4 < 36864) { src = G1; base4 = 32768; }
    else if (i4 < 40960) { src = G2; base4 = 36864; }
    else if (i4 < 49152) { src = GT; base4 = 40960; }
    else                 { src = Wc; base4 = 49152; }
    float4 v = ((const float4*)src)[i4 - base4];
    ushort4 o;
    o.x = f2bf(v.x); o.y = f2bf(v.y); o.z = f2bf(v.z); o.w = f2bf(v.w);
    ((ushort4*)ws)[i4] = o;
}

// ---- main fused kernel: gather + 5 MFMA stages, 6 barriers, deep load overlap ----
__global__ __launch_bounds__(NTHREADS) void hyper6(
    const float* __restrict__ x, const float* __restrict__ sf,
    const int* __restrict__ idx,
    const unsigned short* __restrict__ wsb,
    float* __restrict__ out)
{
    __shared__ __align__(16) unsigned short Xbuf[2][BM][NFEAT]; // 32 KB (normalized bf16 X)
    __shared__ __align__(16) unsigned short Hbuf[2][BM][NHID];  // 8 KB
    __shared__ float scl2[BM];

    unsigned short* G12 = &Xbuf[0][0][0];                 // [2][16][128] (X dead after B)
    unsigned short* FIX = &Xbuf[0][0][0] + 4096;          // [16][128]
    float*          LOG = (float*)(&Xbuf[0][0][0] + 6144);// [16][80]

    const unsigned short* W0p = wsb;
    const unsigned short* W1p = wsb + 65536;
    const unsigned short* G1p = wsb + 131072;
    const unsigned short* G2p = wsb + 147456;
    const unsigned short* GTp = wsb + 163840;
    const unsigned short* Wcp = wsb + 196608;

    const int tid  = threadIdx.x;
    const int bid  = blockIdx.x;
    const int w    = tid >> 6;
    const int lane = tid & 63;
    const int ln   = lane & 15, lg = lane >> 4;
    const int tB = w >> 2, nq = w & 3;
    const unsigned short* Wp = tB ? W1p : W0p;
    const f32x4 zero4 = {0.f, 0.f, 0.f, 0.f};

    // ---- gather: wave w owns rows p = 4w..4w+3 (p = t*16+m). Issue all loads first. ----
    float4 gv[8];
    {
        const float* srcs[4];
        #pragma unroll
        for (int j = 0; j < 4; ++j) {
            int p = w * 4 + j, t = p >> 4, m = p & 15;
            int ri = idx[bid * BM + m];
            srcs[j] = (t ? sf : x) + (size_t)ri * NFEAT + lane * 8;
        }
        #pragma unroll
        for (int j = 0; j < 4; ++j) {
            gv[2 * j]     = ((const float4*)srcs[j])[0];
            gv[2 * j + 1] = ((const float4*)srcs[j])[1];
        }
    }
    // stage-B kc=0 weight fragments: issue now, complete during gather math
    bf16x8 b0 = *(const bf16x8*)(Wp + (size_t)(nq * 32 + ln) * NFEAT + lg * 8);
    bf16x8 b1 = *(const bf16x8*)(Wp + (size_t)(nq * 32 + 16 + ln) * NFEAT + lg * 8);

    // gather math: sumsq reduce, fold 1/||row|| into stored X, store swizzled bf16
    {
        char* xb = (char*)&Xbuf[0][0][0];
        #pragma unroll
        for (int j = 0; j < 4; ++j) {
            int p = w * 4 + j, t = p >> 4, m = p & 15;
            float4 a = gv[2 * j], b = gv[2 * j + 1];
            float ss = a.x*a.x + a.y*a.y + a.z*a.z + a.w*a.w
                     + b.x*b.x + b.y*b.y + b.z*b.z + b.w*b.w;
            #pragma unroll
            for (int d = 1; d < 64; d <<= 1) ss += __shfl_xor(ss, d);
            float scl = (ss > 0.f) ? (1.f / sqrtf(ss)) : 0.f;
            int soff = t * 16384 + m * 1024 + ((lane * 16) ^ ((m & 7) << 4));
            *(bf16x8*)(xb + soff) = pack8s(a, b, scl);
        }
    }
    __syncthreads();   // b1

    // ---- stage B: H[t] = relu(X'[t] @ W[t]^T); K=512 pipelined, 4 acc chains ----
    {
        f32x4 a0e = zero4, a0o = zero4, a1e = zero4, a1o = zero4;
        const unsigned short* Xb = (const unsigned short*)((const char*)&Xbuf[0][0][0] + tB * 16384);
        #pragma unroll
        for (int kc = 0; kc < 16; ++kc) {
            bf16x8 cur0 = b0, cur1 = b1;
            if (kc < 15) {
                b0 = *(const bf16x8*)(Wp + (size_t)(nq * 32 + ln) * NFEAT + (kc + 1) * 32 + lg * 8);
                b1 = *(const bf16x8*)(Wp + (size_t)(nq * 32 + 16 + ln) * NFEAT + (kc + 1) * 32 + lg * 8);
            }
            bf16x8 a = ldsAx(Xb, ln, kc * 64 + lg * 16, 1024);
            if (kc & 1) { a0o = MFMA(a, cur0, a0o); a1o = MFMA(a, cur1, a1o); }
            else        { a0e = MFMA(a, cur0, a0e); a1e = MFMA(a, cur1, a1e); }
        }
        f32x4 acc0 = a0e + a0o, acc1 = a1e + a1o;
        unsigned short* Hb = &Hbuf[tB][0][0];
        #pragma unroll
        for (int rg = 0; rg < 4; ++rg) {
            int m = lg * 4 + rg;
            ldsW1(Hb, m, nq * 32 + ln,      f2bf(fmaxf(acc0[rg], 0.f)));
            ldsW1(Hb, m, nq * 32 + 16 + ln, f2bf(fmaxf(acc1[rg], 0.f)));
        }
    }
    // preload ALL stage-C fragments (independent of H) before the barrier
    bf16x8 cf[8];
    {
        const unsigned short* Gp = tB ? G2p : G1p;
        #pragma unroll
        for (int kc = 0; kc < 4; ++kc)
            #pragma unroll
            for (int nt = 0; nt < 2; ++nt)
                cf[kc * 2 + nt] = *(const bf16x8*)(Gp + (size_t)(nq * 32 + nt * 16 + ln) * NHID + kc * 32 + lg * 8);
    }
    __syncthreads();   // b2

    // ---- stage C: gate1/gate2 = H[t] @ G{1,2}^T ----
    {
        const unsigned short* Hs = &Hbuf[tB][0][0];
        f32x4 accC[2] = {zero4, zero4};
        #pragma unroll
        for (int kc = 0; kc < 4; ++kc) {
            bf16x8 a = ldsAx(Hs, ln, kc * 64 + lg * 16, 256);
            accC[0] = MFMA(a, cf[kc * 2],     accC[0]);
            accC[1] = MFMA(a, cf[kc * 2 + 1], accC[1]);
        }
        unsigned short* Gd = G12 + tB * 2048;
        #pragma unroll
        for (int nt = 0; nt < 2; ++nt)
            #pragma unroll
            for (int rg = 0; rg < 4; ++rg) {
                int m = lg * 4 + rg;
                ldsW1(Gd, m, nq * 32 + nt * 16 + ln, f2bf(accC[nt][rg]));
            }
    }
    __syncthreads();   // b3

    // ---- stage D: gate = sigmoid([g1,g2] @ GT^T); fix = (1-g)H0 + gH1; 2 chains ----
    {
        f32x4 accE_ = zero4, accO_ = zero4;
        const int n = w * 16 + ln;
        #pragma unroll
        for (int kc = 0; kc < 8; ++kc) {
            const unsigned short* As = G12 + (kc >> 2) * 2048;
            bf16x8 a = ldsAx(As, ln, (kc & 3) * 64 + lg * 16, 256);
            bf16x8 b = *(const bf16x8*)(GTp + (size_t)n * (2 * NHID) + kc * 32 + lg * 8);
            if (kc & 1) accO_ = MFMA(a, b, accO_); else accE_ = MFMA(a, b, accE_);
        }
        f32x4 accD = accE_ + accO_;
        #pragma unroll
        for (int rg = 0; rg < 4; ++rg) {
            int m = lg * 4 + rg;
            float g  = 1.f / (1.f + __expf(-accD[rg]));
            float h0 = ldsR1(&Hbuf[0][0][0], m, n);
            float h1 = ldsR1(&Hbuf[1][0][0], m, n);
            ldsW1(FIX, m, n, f2bf((1.f - g) * h0 + g * h1));
        }
    }
    __syncthreads();   // b4

    // ---- fix_inner row norms -> scl2 ----
    if (tid < 256) {
        int r = tid >> 4, sl = tid & 15;
        bf16x8 v = ldsAx(FIX, r, sl * 16, 256);
        float ss = 0.f;
        #pragma unroll
        for (int j = 0; j < 8; ++j) { float f = (float)v[j]; ss += f * f; }
        ss += __shfl_xor(ss, 1); ss += __shfl_xor(ss, 2);
        ss += __shfl_xor(ss, 4); ss += __shfl_xor(ss, 8);
        if (sl == 0) scl2[r] = (ss > 0.f) ? (1.f / sqrtf(ss)) : 0.f;
    }
    __syncthreads();   // b5

    // ---- stage E: logits = relu(scl2 * fix @ Wc^T) ----
    if (w < 5) {
        const int cc = w * 16 + ln;
        bf16x8 bfz;
        #pragma unroll
        for (int j = 0; j < 8; ++j) bfz[j] = (__bf16)0.f;
        f32x4 accE = zero4;
        #pragma unroll
        for (int kc = 0; kc < 4; ++kc) {
            bf16x8 a = ldsAx(FIX, ln, kc * 64 + lg * 16, 256);
            bf16x8 b = (cc < NCLASS) ? *(const bf16x8*)(Wcp + (size_t)cc * NHID + kc * 32 + lg * 8) : bfz;
            accE = MFMA(a, b, accE);
        }
        #pragma unroll
        for (int rg = 0; rg < 4; ++rg) {
            int m = lg * 4 + rg;
            float v = fmaxf(accE[rg] * scl2[m], 0.f);
            LOG[m * 80 + cc] = (cc < NCLASS) ? v : -1e30f;
        }
    }
    __syncthreads();   // b6

    // ---- log_softmax + store ----
    {
        const int r = tid >> 5, l32 = tid & 31;
        float v0 = LOG[r * 80 + l32];
        float v1 = LOG[r * 80 + 32 + l32];
        float v2 = (l32 < 16) ? LOG[r * 80 + 64 + l32] : -1e30f;
        float mx = fmaxf(fmaxf(v0, v1), v2);
        #pragma unroll
        for (int d = 1; d < 32; d <<= 1) mx = fmaxf(mx, __shfl_xor(mx, d, 32));
        float se = __expf(v0 - mx) + __expf(v1 - mx) + ((l32 < 16) ? __expf(v2 - mx) : 0.f);
        #pragma unroll
        for (int d = 1; d < 32; d <<= 1) se += __shfl_xor(se, d, 32);
        float lz = mx + __logf(se);
        size_t orow = (size_t)bid * BM + r;
        out[orow * NCLASS + l32] = v0 - lz;
        if (l32 + 32 < NCLASS) out[orow * NCLASS + 32 + l32] = v1 - lz;
        if (l32 + 64 < NCLASS) out[orow * NCLASS + 64 + l32] = v2 - lz;
    }
}

// ---- fallback (ws too small): fused kernel with inline f32->bf16 weight fragments ----
static __device__ __forceinline__ bf16x8 bfragF(const float* p, size_t off) {
    const float4* q = (const float4*)(p + off);
    return pack8(q[0], q[1]);
}
__global__ __launch_bounds__(NTHREADS) void hyper_fb(
    const float* __restrict__ x, const float* __restrict__ sf,
    const int* __restrict__ idx,
    const float* __restrict__ W0, const float* __restrict__ W1,
    const float* __restrict__ G1, const float* __restrict__ G2,
    const float* __restrict__ GT, const float* __restrict__ Wc,
    float* __restrict__ out)
{
    __shared__ __align__(16) unsigned short Xbuf[2][BM][NFEAT];
    __shared__ __align__(16) unsigned short Hbuf[2][BM][NHID];
    __shared__ float scl2[BM];
    unsigned short* G12 = &Xbuf[0][0][0];
    unsigned short* FIX = &Xbuf[0][0][0] + 4096;
    float*          LOG = (float*)(&Xbuf[0][0][0] + 6144);

    const int tid = threadIdx.x, bid = blockIdx.x;
    const int w = tid >> 6, lane = tid & 63;
    const int ln = lane & 15, lg = lane >> 4;
    const int tB = w >> 2, nq = w & 3;
    const f32x4 zero4 = {0.f, 0.f, 0.f, 0.f};

    {
        char* xb = (char*)&Xbuf[0][0][0];
        #pragma unroll
        for (int j = 0; j < 4; ++j) {
            int p = w * 4 + j, t = p >> 4, m = p & 15;
            int ri = idx[bid * BM + m];
            const float4* q = (const float4*)((t ? sf : x) + (size_t)ri * NFEAT + lane * 8);
            float4 a = q[0], b = q[1];
            float ss = a.x*a.x + a.y*a.y + a.z*a.z + a.w*a.w
                     + b.x*b.x + b.y*b.y + b.z*b.z + b.w*b.w;
            #pragma unroll
            for (int d = 1; d < 64; d <<= 1) ss += __shfl_xor(ss, d);
            float scl = (ss > 0.f) ? (1.f / sqrtf(ss)) : 0.f;
            int soff = t * 16384 + m * 1024 + ((lane * 16) ^ ((m & 7) << 4));
            *(bf16x8*)(xb + soff) = pack8s(a, b, scl);
        }
    }
    __syncthreads();
    {
        const float* Wp = tB ? W1 : W0;
        f32x4 acc0 = zero4, acc1 = zero4;
        const unsigned short* Xb = (const unsigned short*)((const char*)&Xbuf[0][0][0] + tB * 16384);
        #pragma unroll
        for (int kc = 0; kc < 16; ++kc) {
            bf16x8 a = ldsAx(Xb, ln, kc * 64 + lg * 16, 1024);
            acc0 = MFMA(a, bfragF(Wp, (size_t)(nq * 32 + ln) * NFEAT + kc * 32 + lg * 8), acc0);
            acc1 = MFMA(a, bfragF(Wp, (size_t)(nq * 32 + 16 + ln) * NFEAT + kc * 32 + lg * 8), acc1);
        }
        unsigned short* Hb = &Hbuf[tB][0][0];
        #pragma unroll
        for (int rg = 0; rg < 4; ++rg) {
            int m = lg * 4 + rg;
            ldsW1(Hb, m, nq * 32 + ln,      f2bf(fmaxf(acc0[rg], 0.f)));
            ldsW1(Hb, m, nq * 32 + 16 + ln, f2bf(fmaxf(acc1[rg], 0.f)));
        }
    }
    __syncthreads();
    {
        const float* Gp = tB ? G2 : G1;
        const unsigned short* Hs = &Hbuf[tB][0][0];
        f32x4 accC[2] = {zero4, zero4};
        #pragma unroll
        for (int kc = 0; kc < 4; ++kc) {
            bf16x8 a = ldsAx(Hs, ln, kc * 64 + lg * 16, 256);
            accC[0] = MFMA(a, bfragF(Gp, (size_t)(nq * 32 + ln) * NHID + kc * 32 + lg * 8), accC[0]);
            accC[1] = MFMA(a, bfragF(Gp, (size_t)(nq * 32 + 16 + ln) * NHID + kc * 32 + lg * 8), accC[1]);
        }
        unsigned short* Gd = G12 + tB * 2048;
        #pragma unroll
        for (int nt = 0; nt < 2; ++nt)
            #pragma unroll
            for (int rg = 0; rg < 4; ++rg) {
                int m = lg * 4 + rg;
                ldsW1(Gd, m, nq * 32 + nt * 16 + ln, f2bf(accC[nt][rg]));
            }
    }
    __syncthreads();
    {
        f32x4 accD = zero4;
        const int n = w * 16 + ln;
        #pragma unroll
        for (int kc = 0; kc < 8; ++kc) {
            const unsigned short* As = G12 + (kc >> 2) * 2048;
            bf16x8 a = ldsAx(As, ln, (kc & 3) * 64 + lg * 16, 256);
            accD = MFMA(a, bfragF(GT, (size_t)n * (2 * NHID) + kc * 32 + lg * 8), accD);
        }
        #pragma unroll
        for (int rg = 0; rg < 4; ++rg) {
            int m = lg * 4 + rg;
            float g  = 1.f / (1.f + __expf(-accD[rg]));
            float h0 = ldsR1(&Hbuf[0][0][0], m, n);
            float h1 = ldsR1(&Hbuf[1][0][0], m, n);
            ldsW1(FIX, m, n, f2bf((1.f - g) * h0 + g * h1));
        }
    }
    __syncthreads();
    if (tid < 256) {
        int r = tid >> 4, sl = tid & 15;
        bf16x8 v = ldsAx(FIX, r, sl * 16, 256);
        float ss = 0.f;
        #pragma unroll
        for (int j = 0; j < 8; ++j) { float f = (float)v[j]; ss += f * f; }
        ss += __shfl_xor(ss, 1); ss += __shfl_xor(ss, 2);
        ss += __shfl_xor(ss, 4); ss += __shfl_xor(ss, 8);
        if (sl == 0) scl2[r] = (ss > 0.f) ? (1.f / sqrtf(ss)) : 0.f;
    }
    __syncthreads();
    if (w < 5) {
        const int cc = w * 16 + ln;
        bf16x8 bfz;
        #pragma unroll
        for (int j = 0; j < 8; ++j) bfz[j] = (__bf16)0.f;
        f32x4 accE = zero4;
        #pragma unroll
        for (int kc = 0; kc < 4; ++kc) {
            bf16x8 a = ldsAx(FIX, ln, kc * 64 + lg * 16, 256);
            bf16x8 b = (cc < NCLASS) ? bfragF(Wc, (size_t)cc * NHID + kc * 32 + lg * 8) : bfz;
            accE = MFMA(a, b, accE);
        }
        #pragma unroll
        for (int rg = 0; rg < 4; ++rg) {
            int m = lg * 4 + rg;
            float v = fmaxf(accE[rg] * scl2[m], 0.f);
            LOG[m * 80 + cc] = (cc < NCLASS) ? v : -1e30f;
        }
    }
    __syncthreads();
    {
        const int r = tid >> 5, l32 = tid & 31;
        float v0 = LOG[r * 80 + l32];
        float v1 = LOG[r * 80 + 32 + l32];
        float v2 = (l32 < 16) ? LOG[r * 80 + 64 + l32] : -1e30f;
        float mx = fmaxf(fmaxf(v0, v1), v2);
        #pragma unroll
        for (int d = 1; d < 32; d <<= 1) mx = fmaxf(mx, __shfl_xor(mx, d, 32));
        float se = __expf(v0 - mx) + __expf(v1 - mx) + ((l32 < 16) ? __expf(v2 - mx) : 0.f);
        #pragma unroll
        for (int d = 1; d < 32; d <<= 1) se += __shfl_xor(se, d, 32);
        float lz = mx + __logf(se);
        size_t orow = (size_t)bid * BM + r;
        out[orow * NCLASS + l32] = v0 - lz;
        if (l32 + 32 < NCLASS) out[orow * NCLASS + 32 + l32] = v1 - lz;
        if (l32 + 64 < NCLASS) out[orow * NCLASS + 64 + l32] = v2 - lz;
    }
}

extern "C" void kernel_launch(void* const* d_in, const int* in_sizes, int n_in,
                              void* d_out, int out_size, void* d_ws, size_t ws_size,
                              hipStream_t stream)
{
    const float* x   = (const float*)d_in[0];
    const float* sf  = (const float*)d_in[1];
    const int*   idx = (const int*)d_in[2];
    const float* W0  = (const float*)d_in[3];
    const float* W1  = (const float*)d_in[4];
    const float* G1  = (const float*)d_in[5];
    const float* G2  = (const float*)d_in[6];
    const float* GT  = (const float*)d_in[7];
    const float* Wc  = (const float*)d_in[8];
    float* out = (float*)d_out;

    if (ws_size >= WS_NEED) {
        unsigned short* ws = (unsigned short*)d_ws;
        prep_weights<<<dim3(PREP_BLKS), dim3(256), 0, stream>>>(W0, W1, G1, G2, GT, Wc, ws);
        hyper6<<<dim3(NBLK), dim3(NTHREADS), 0, stream>>>(x, sf, idx, ws, out);
    } else {
        hyper_fb<<<dim3(NBLK), dim3(NTHREADS), 0, stream>>>(
            x, sf, idx, W0, W1, G1, G2, GT, Wc, out);
    }
}

// Round 7
// 50.121 us; speedup vs baseline: 1.1959x; 1.0184x over previous
//
#include <hip/hip_runtime.h>
#include <math.h>

#define NFEAT  512
#define NHID   128
#define NCLASS 70
#define NIDX   10000
#define NTILE  625                    // 625 tiles x 16 rows
#define W4TOT  51392
#define PREP_BLKS ((W4TOT + 255) / 256)
#define HELEMS (2u * NIDX * NHID)     // 2,560,000 ushorts (H scratch)
#define WS_NEED ((size_t)(HELEMS + 205568) * 2)

typedef float  f32x4  __attribute__((ext_vector_type(4)));
typedef __bf16 bf16x8 __attribute__((ext_vector_type(8)));

static __device__ __forceinline__ unsigned short f2bf(float f) {
    unsigned u = __builtin_bit_cast(unsigned, f);
    u += 0x7fffu + ((u >> 16) & 1u);
    return (unsigned short)(u >> 16);
}
static __device__ __forceinline__ float bf2f(unsigned short h) {
    unsigned u = ((unsigned)h) << 16;
    return __builtin_bit_cast(float, u);
}
static __device__ __forceinline__ bf16x8 pack8(float4 a, float4 b) {
    bf16x8 r;
    r[0] = (__bf16)a.x; r[1] = (__bf16)a.y; r[2] = (__bf16)a.z; r[3] = (__bf16)a.w;
    r[4] = (__bf16)b.x; r[5] = (__bf16)b.y; r[6] = (__bf16)b.z; r[7] = (__bf16)b.w;
    return r;
}
static __device__ __forceinline__ bf16x8 pack8s(float4 a, float4 b, float s) {
    bf16x8 r;
    r[0] = (__bf16)(a.x * s); r[1] = (__bf16)(a.y * s); r[2] = (__bf16)(a.z * s); r[3] = (__bf16)(a.w * s);
    r[4] = (__bf16)(b.x * s); r[5] = (__bf16)(b.y * s); r[6] = (__bf16)(b.z * s); r[7] = (__bf16)(b.w * s);
    return r;
}
static __device__ __forceinline__ f32x4 MFMA(bf16x8 a, bf16x8 b, f32x4 c) {
    return __builtin_amdgcn_mfma_f32_16x16x32_bf16(a, b, c, 0, 0, 0);
}
static __device__ __forceinline__ bf16x8 ldsAx(const unsigned short* base, int row, int colb, int rstride) {
    return *(const bf16x8*)((const char*)base + row * rstride + (colb ^ ((row & 7) << 4)));
}
static __device__ __forceinline__ void ldsW1(unsigned short* base, int row, int col, unsigned short v) {
    *(unsigned short*)((char*)base + row * 256 + ((col * 2) ^ ((row & 7) << 4))) = v;
}
static __device__ __forceinline__ float ldsR1(const unsigned short* base, int row, int col) {
    return bf2f(*(const unsigned short*)((const char*)base + row * 256 + ((col * 2) ^ ((row & 7) << 4))));
}

// ---- prep: all weights f32 -> bf16 into weight region of d_ws ----
__global__ void prep_weights(const float* __restrict__ W0, const float* __restrict__ W1,
                             const float* __restrict__ G1, const float* __restrict__ G2,
                             const float* __restrict__ GT, const float* __restrict__ Wc,
                             unsigned short* __restrict__ wsW) {
    int i4 = blockIdx.x * 256 + threadIdx.x;
    if (i4 >= W4TOT) return;
    const float* src; int base4;
    if      (i4 < 16384) { src = W0; base4 = 0; }
    else if (i4 < 32768) { src = W1; base4 = 16384; }
    else if (i4 < 36864) { src = G1; base4 = 32768; }
    else if (i4 < 40960) { src = G2; base4 = 36864; }
    else if (i4 < 49152) { src = GT; base4 = 40960; }
    else                 { src = Wc; base4 = 49152; }
    float4 v = ((const float4*)src)[i4 - base4];
    ushort4 o;
    o.x = f2bf(v.x); o.y = f2bf(v.y); o.z = f2bf(v.z); o.w = f2bf(v.w);
    ((ushort4*)wsW)[i4] = o;
}

// ---- kernel A: per-(tile,tensor) gather + normalize + stage B; H -> ws ----
// 1250 blocks x 256 threads; 2 barriers; H stored with swizzle baked in.
__global__ __launch_bounds__(256) void stageB(
    const float* __restrict__ x, const float* __restrict__ sf,
    const int* __restrict__ idx,
    const unsigned short* __restrict__ wsW,
    unsigned short* __restrict__ wsH)
{
    __shared__ __align__(16) unsigned short X[16][NFEAT];   // 16 KB, swizzled bf16
    __shared__ __align__(16) unsigned short Hls[16][NHID];  // 4 KB, swizzled bf16

    const int bid  = blockIdx.x;
    const int t    = bid & 1, tile = bid >> 1;
    const int tid  = threadIdx.x;
    const int w    = tid >> 6;          // wave 0..3
    const int lane = tid & 63;
    const int ln   = lane & 15, lg = lane >> 4;
    const float* base = t ? sf : x;
    const unsigned short* Wp = wsW + (size_t)t * 65536;
    const f32x4 zero4 = {0.f, 0.f, 0.f, 0.f};

    // gather: wave w owns rows m = 4j + w; issue all loads first
    float4 gv[8];
    #pragma unroll
    for (int j = 0; j < 4; ++j) {
        int m = j * 4 + w;
        const float4* q = (const float4*)(base + (size_t)idx[tile * 16 + m] * NFEAT + lane * 8);
        gv[2 * j]     = q[0];
        gv[2 * j + 1] = q[1];
    }
    // prefetch stage-B kc=0 weight fragments under the gather math
    bf16x8 b0 = *(const bf16x8*)(Wp + (size_t)(w * 32 + ln) * NFEAT + lg * 8);
    bf16x8 b1 = *(const bf16x8*)(Wp + (size_t)(w * 32 + 16 + ln) * NFEAT + lg * 8);

    {
        char* xb = (char*)&X[0][0];
        #pragma unroll
        for (int j = 0; j < 4; ++j) {
            int m = j * 4 + w;
            float4 a = gv[2 * j], b = gv[2 * j + 1];
            float ss = a.x*a.x + a.y*a.y + a.z*a.z + a.w*a.w
                     + b.x*b.x + b.y*b.y + b.z*b.z + b.w*b.w;
            #pragma unroll
            for (int d = 1; d < 64; d <<= 1) ss += __shfl_xor(ss, d);
            float scl = (ss > 0.f) ? (1.f / sqrtf(ss)) : 0.f;
            *(bf16x8*)(xb + m * 1024 + ((lane * 16) ^ ((m & 7) << 4))) = pack8s(a, b, scl);
        }
    }
    __syncthreads();

    // stage B: H = relu(X' @ W^T); wave w -> cols w*32..w*32+31; pipelined, 4 chains
    {
        f32x4 a0e = zero4, a0o = zero4, a1e = zero4, a1o = zero4;
        #pragma unroll
        for (int kc = 0; kc < 16; ++kc) {
            bf16x8 cur0 = b0, cur1 = b1;
            if (kc < 15) {
                b0 = *(const bf16x8*)(Wp + (size_t)(w * 32 + ln) * NFEAT + (kc + 1) * 32 + lg * 8);
                b1 = *(const bf16x8*)(Wp + (size_t)(w * 32 + 16 + ln) * NFEAT + (kc + 1) * 32 + lg * 8);
            }
            bf16x8 a = ldsAx(&X[0][0], ln, kc * 64 + lg * 16, 1024);
            if (kc & 1) { a0o = MFMA(a, cur0, a0o); a1o = MFMA(a, cur1, a1o); }
            else        { a0e = MFMA(a, cur0, a0e); a1e = MFMA(a, cur1, a1e); }
        }
        f32x4 acc0 = a0e + a0o, acc1 = a1e + a1o;
        #pragma unroll
        for (int rg = 0; rg < 4; ++rg) {
            int m = lg * 4 + rg;
            ldsW1(&Hls[0][0], m, w * 32 + ln,      f2bf(fmaxf(acc0[rg], 0.f)));
            ldsW1(&Hls[0][0], m, w * 32 + 16 + ln, f2bf(fmaxf(acc1[rg], 0.f)));
        }
    }
    __syncthreads();

    // copy H tile (swizzle baked) to global scratch: 256 thr x 16 B = 4 KB exact
    uint4 v = ((const uint4*)&Hls[0][0])[tid];
    ((uint4*)(wsH + ((size_t)t * NIDX + (size_t)tile * 16) * NHID))[tid] = v;
}

// ---- kernel B: per-tile stages C/D/E + softmax; H from ws (L2-resident) ----
__global__ __launch_bounds__(512) void tailCDE(
    const unsigned short* __restrict__ wsW,
    const unsigned short* __restrict__ wsH,
    float* __restrict__ out)
{
    __shared__ __align__(16) unsigned short Hbuf[2][16][NHID]; // 8 KB (swizzle baked)
    __shared__ __align__(16) unsigned short Scr[8704];         // G12 | FIX | LOG
    __shared__ float scl2[16];

    unsigned short* G12 = Scr;                // [2][16][128]
    unsigned short* FIX = Scr + 4096;         // [16][128]
    float*          LOG = (float*)(Scr + 6144); // [16][80]

    const unsigned short* G1p = wsW + 131072;
    const unsigned short* G2p = wsW + 147456;
    const unsigned short* GTp = wsW + 163840;
    const unsigned short* Wcp = wsW + 196608;

    const int tid  = threadIdx.x;
    const int bid  = blockIdx.x;
    const int w    = tid >> 6;
    const int lane = tid & 63;
    const int ln   = lane & 15, lg = lane >> 4;
    const int tB = w >> 2, nq = w & 3;
    const f32x4 zero4 = {0.f, 0.f, 0.f, 0.f};

    // load both H tiles: 512 thr x 16 B = 8 KB exact
    {
        int tt = tid >> 8, r = tid & 255;
        uint4 v = *(const uint4*)((const char*)wsH
                    + ((size_t)tt * NIDX + (size_t)bid * 16) * 256 + r * 16);
        ((uint4*)&Hbuf[0][0][0])[tid] = v;
    }
    // preload all stage-C fragments (independent of H)
    bf16x8 cf[8];
    {
        const unsigned short* Gp = tB ? G2p : G1p;
        #pragma unroll
        for (int kc = 0; kc < 4; ++kc)
            #pragma unroll
            for (int nt = 0; nt < 2; ++nt)
                cf[kc * 2 + nt] = *(const bf16x8*)(Gp + (size_t)(nq * 32 + nt * 16 + ln) * NHID + kc * 32 + lg * 8);
    }
    __syncthreads();

    // stage C: gate1/gate2 = H[t] @ G{1,2}^T
    {
        const unsigned short* Hs = &Hbuf[tB][0][0];
        f32x4 accC[2] = {zero4, zero4};
        #pragma unroll
        for (int kc = 0; kc < 4; ++kc) {
            bf16x8 a = ldsAx(Hs, ln, kc * 64 + lg * 16, 256);
            accC[0] = MFMA(a, cf[kc * 2],     accC[0]);
            accC[1] = MFMA(a, cf[kc * 2 + 1], accC[1]);
        }
        unsigned short* Gd = G12 + tB * 2048;
        #pragma unroll
        for (int nt = 0; nt < 2; ++nt)
            #pragma unroll
            for (int rg = 0; rg < 4; ++rg) {
                int m = lg * 4 + rg;
                ldsW1(Gd, m, nq * 32 + nt * 16 + ln, f2bf(accC[nt][rg]));
            }
    }
    __syncthreads();

    // stage D: gate = sigmoid([g1,g2] @ GT^T); fix = (1-g)H0 + gH1
    {
        f32x4 accE_ = zero4, accO_ = zero4;
        const int n = w * 16 + ln;
        #pragma unroll
        for (int kc = 0; kc < 8; ++kc) {
            const unsigned short* As = G12 + (kc >> 2) * 2048;
            bf16x8 a = ldsAx(As, ln, (kc & 3) * 64 + lg * 16, 256);
            bf16x8 b = *(const bf16x8*)(GTp + (size_t)n * (2 * NHID) + kc * 32 + lg * 8);
            if (kc & 1) accO_ = MFMA(a, b, accO_); else accE_ = MFMA(a, b, accE_);
        }
        f32x4 accD = accE_ + accO_;
        #pragma unroll
        for (int rg = 0; rg < 4; ++rg) {
            int m = lg * 4 + rg;
            float g  = 1.f / (1.f + __expf(-accD[rg]));
            float h0 = ldsR1(&Hbuf[0][0][0], m, n);
            float h1 = ldsR1(&Hbuf[1][0][0], m, n);
            ldsW1(FIX, m, n, f2bf((1.f - g) * h0 + g * h1));
        }
    }
    __syncthreads();

    // fix_inner row norms -> scl2
    if (tid < 256) {
        int r = tid >> 4, sl = tid & 15;
        bf16x8 v = ldsAx(FIX, r, sl * 16, 256);
        float ss = 0.f;
        #pragma unroll
        for (int j = 0; j < 8; ++j) { float f = (float)v[j]; ss += f * f; }
        ss += __shfl_xor(ss, 1); ss += __shfl_xor(ss, 2);
        ss += __shfl_xor(ss, 4); ss += __shfl_xor(ss, 8);
        if (sl == 0) scl2[r] = (ss > 0.f) ? (1.f / sqrtf(ss)) : 0.f;
    }
    __syncthreads();

    // stage E: logits = relu(scl2 * fix @ Wc^T)
    if (w < 5) {
        const int cc = w * 16 + ln;
        bf16x8 bfz;
        #pragma unroll
        for (int j = 0; j < 8; ++j) bfz[j] = (__bf16)0.f;
        f32x4 accE = zero4;
        #pragma unroll
        for (int kc = 0; kc < 4; ++kc) {
            bf16x8 a = ldsAx(FIX, ln, kc * 64 + lg * 16, 256);
            bf16x8 b = (cc < NCLASS) ? *(const bf16x8*)(Wcp + (size_t)cc * NHID + kc * 32 + lg * 8) : bfz;
            accE = MFMA(a, b, accE);
        }
        #pragma unroll
        for (int rg = 0; rg < 4; ++rg) {
            int m = lg * 4 + rg;
            float v = fmaxf(accE[rg] * scl2[m], 0.f);
            LOG[m * 80 + cc] = (cc < NCLASS) ? v : -1e30f;
        }
    }
    __syncthreads();

    // log_softmax + store
    {
        const int r = tid >> 5, l32 = tid & 31;
        float v0 = LOG[r * 80 + l32];
        float v1 = LOG[r * 80 + 32 + l32];
        float v2 = (l32 < 16) ? LOG[r * 80 + 64 + l32] : -1e30f;
        float mx = fmaxf(fmaxf(v0, v1), v2);
        #pragma unroll
        for (int d = 1; d < 32; d <<= 1) mx = fmaxf(mx, __shfl_xor(mx, d, 32));
        float se = __expf(v0 - mx) + __expf(v1 - mx) + ((l32 < 16) ? __expf(v2 - mx) : 0.f);
        #pragma unroll
        for (int d = 1; d < 32; d <<= 1) se += __shfl_xor(se, d, 32);
        float lz = mx + __logf(se);
        size_t orow = (size_t)bid * 16 + r;
        out[orow * NCLASS + l32] = v0 - lz;
        if (l32 + 32 < NCLASS) out[orow * NCLASS + 32 + l32] = v1 - lz;
        if (l32 + 64 < NCLASS) out[orow * NCLASS + 64 + l32] = v2 - lz;
    }
}

// ---- fallback (ws too small): round-6 fused kernel, f32 weights inline ----
static __device__ __forceinline__ bf16x8 bfragF(const float* p, size_t off) {
    const float4* q = (const float4*)(p + off);
    return pack8(q[0], q[1]);
}
__global__ __launch_bounds__(512) void hyper_fb(
    const float* __restrict__ x, const float* __restrict__ sf,
    const int* __restrict__ idx,
    const float* __restrict__ W0, const float* __restrict__ W1,
    const float* __restrict__ G1, const float* __restrict__ G2,
    const float* __restrict__ GT, const float* __restrict__ Wc,
    float* __restrict__ out)
{
    __shared__ __align__(16) unsigned short Xbuf[2][16][NFEAT];
    __shared__ __align__(16) unsigned short Hbuf[2][16][NHID];
    __shared__ float scl2[16];
    unsigned short* G12 = &Xbuf[0][0][0];
    unsigned short* FIX = &Xbuf[0][0][0] + 4096;
    float*          LOG = (float*)(&Xbuf[0][0][0] + 6144);

    const int tid = threadIdx.x, bid = blockIdx.x;
    const int w = tid >> 6, lane = tid & 63;
    const int ln = lane & 15, lg = lane >> 4;
    const int tB = w >> 2, nq = w & 3;
    const f32x4 zero4 = {0.f, 0.f, 0.f, 0.f};

    {
        char* xb = (char*)&Xbuf[0][0][0];
        #pragma unroll
        for (int j = 0; j < 4; ++j) {
            int p = w * 4 + j, t = p >> 4, m = p & 15;
            int ri = idx[bid * 16 + m];
            const float4* q = (const float4*)((t ? sf : x) + (size_t)ri * NFEAT + lane * 8);
            float4 a = q[0], b = q[1];
            float ss = a.x*a.x + a.y*a.y + a.z*a.z + a.w*a.w
                     + b.x*b.x + b.y*b.y + b.z*b.z + b.w*b.w;
            #pragma unroll
            for (int d = 1; d < 64; d <<= 1) ss += __shfl_xor(ss, d);
            float scl = (ss > 0.f) ? (1.f / sqrtf(ss)) : 0.f;
            int soff = t * 16384 + m * 1024 + ((lane * 16) ^ ((m & 7) << 4));
            *(bf16x8*)(xb + soff) = pack8s(a, b, scl);
        }
    }
    __syncthreads();
    {
        const float* Wp = tB ? W1 : W0;
        f32x4 acc0 = zero4, acc1 = zero4;
        const unsigned short* Xb = (const unsigned short*)((const char*)&Xbuf[0][0][0] + tB * 16384);
        #pragma unroll
        for (int kc = 0; kc < 16; ++kc) {
            bf16x8 a = ldsAx(Xb, ln, kc * 64 + lg * 16, 1024);
            acc0 = MFMA(a, bfragF(Wp, (size_t)(nq * 32 + ln) * NFEAT + kc * 32 + lg * 8), acc0);
            acc1 = MFMA(a, bfragF(Wp, (size_t)(nq * 32 + 16 + ln) * NFEAT + kc * 32 + lg * 8), acc1);
        }
        unsigned short* Hb = &Hbuf[tB][0][0];
        #pragma unroll
        for (int rg = 0; rg < 4; ++rg) {
            int m = lg * 4 + rg;
            ldsW1(Hb, m, nq * 32 + ln,      f2bf(fmaxf(acc0[rg], 0.f)));
            ldsW1(Hb, m, nq * 32 + 16 + ln, f2bf(fmaxf(acc1[rg], 0.f)));
        }
    }
    __syncthreads();
    {
        const float* Gp = tB ? G2 : G1;
        const unsigned short* Hs = &Hbuf[tB][0][0];
        f32x4 accC[2] = {zero4, zero4};
        #pragma unroll
        for (int kc = 0; kc < 4; ++kc) {
            bf16x8 a = ldsAx(Hs, ln, kc * 64 + lg * 16, 256);
            accC[0] = MFMA(a, bfragF(Gp, (size_t)(nq * 32 + ln) * NHID + kc * 32 + lg * 8), accC[0]);
            accC[1] = MFMA(a, bfragF(Gp, (size_t)(nq * 32 + 16 + ln) * NHID + kc * 32 + lg * 8), accC[1]);
        }
        unsigned short* Gd = G12 + tB * 2048;
        #pragma unroll
        for (int nt = 0; nt < 2; ++nt)
            #pragma unroll
            for (int rg = 0; rg < 4; ++rg) {
                int m = lg * 4 + rg;
                ldsW1(Gd, m, nq * 32 + nt * 16 + ln, f2bf(accC[nt][rg]));
            }
    }
    __syncthreads();
    {
        f32x4 accD = zero4;
        const int n = w * 16 + ln;
        #pragma unroll
        for (int kc = 0; kc < 8; ++kc) {
            const unsigned short* As = G12 + (kc >> 2) * 2048;
            bf16x8 a = ldsAx(As, ln, (kc & 3) * 64 + lg * 16, 256);
            accD = MFMA(a, bfragF(GT, (size_t)n * (2 * NHID) + kc * 32 + lg * 8), accD);
        }
        #pragma unroll
        for (int rg = 0; rg < 4; ++rg) {
            int m = lg * 4 + rg;
            float g  = 1.f / (1.f + __expf(-accD[rg]));
            float h0 = ldsR1(&Hbuf[0][0][0], m, n);
            float h1 = ldsR1(&Hbuf[1][0][0], m, n);
            ldsW1(FIX, m, n, f2bf((1.f - g) * h0 + g * h1));
        }
    }
    __syncthreads();
    if (tid < 256) {
        int r = tid >> 4, sl = tid & 15;
        bf16x8 v = ldsAx(FIX, r, sl * 16, 256);
        float ss = 0.f;
        #pragma unroll
        for (int j = 0; j < 8; ++j) { float f = (float)v[j]; ss += f * f; }
        ss += __shfl_xor(ss, 1); ss += __shfl_xor(ss, 2);
        ss += __shfl_xor(ss, 4); ss += __shfl_xor(ss, 8);
        if (sl == 0) scl2[r] = (ss > 0.f) ? (1.f / sqrtf(ss)) : 0.f;
    }
    __syncthreads();
    if (w < 5) {
        const int cc = w * 16 + ln;
        bf16x8 bfz;
        #pragma unroll
        for (int j = 0; j < 8; ++j) bfz[j] = (__bf16)0.f;
        f32x4 accE = zero4;
        #pragma unroll
        for (int kc = 0; kc < 4; ++kc) {
            bf16x8 a = ldsAx(FIX, ln, kc * 64 + lg * 16, 256);
            bf16x8 b = (cc < NCLASS) ? bfragF(Wc, (size_t)cc * NHID + kc * 32 + lg * 8) : bfz;
            accE = MFMA(a, b, accE);
        }
        #pragma unroll
        for (int rg = 0; rg < 4; ++rg) {
            int m = lg * 4 + rg;
            float v = fmaxf(accE[rg] * scl2[m], 0.f);
            LOG[m * 80 + cc] = (cc < NCLASS) ? v : -1e30f;
        }
    }
    __syncthreads();
    {
        const int r = tid >> 5, l32 = tid & 31;
        float v0 = LOG[r * 80 + l32];
        float v1 = LOG[r * 80 + 32 + l32];
        float v2 = (l32 < 16) ? LOG[r * 80 + 64 + l32] : -1e30f;
        float mx = fmaxf(fmaxf(v0, v1), v2);
        #pragma unroll
        for (int d = 1; d < 32; d <<= 1) mx = fmaxf(mx, __shfl_xor(mx, d, 32));
        float se = __expf(v0 - mx) + __expf(v1 - mx) + ((l32 < 16) ? __expf(v2 - mx) : 0.f);
        #pragma unroll
        for (int d = 1; d < 32; d <<= 1) se += __shfl_xor(se, d, 32);
        float lz = mx + __logf(se);
        size_t orow = (size_t)bid * 16 + r;
        out[orow * NCLASS + l32] = v0 - lz;
        if (l32 + 32 < NCLASS) out[orow * NCLASS + 32 + l32] = v1 - lz;
        if (l32 + 64 < NCLASS) out[orow * NCLASS + 64 + l32] = v2 - lz;
    }
}

extern "C" void kernel_launch(void* const* d_in, const int* in_sizes, int n_in,
                              void* d_out, int out_size, void* d_ws, size_t ws_size,
                              hipStream_t stream)
{
    const float* x   = (const float*)d_in[0];
    const float* sf  = (const float*)d_in[1];
    const int*   idx = (const int*)d_in[2];
    const float* W0  = (const float*)d_in[3];
    const float* W1  = (const float*)d_in[4];
    const float* G1  = (const float*)d_in[5];
    const float* G2  = (const float*)d_in[6];
    const float* GT  = (const float*)d_in[7];
    const float* Wc  = (const float*)d_in[8];
    float* out = (float*)d_out;

    if (ws_size >= WS_NEED) {
        unsigned short* wsH = (unsigned short*)d_ws;
        unsigned short* wsW = wsH + HELEMS;
        prep_weights<<<dim3(PREP_BLKS), dim3(256), 0, stream>>>(W0, W1, G1, G2, GT, Wc, wsW);
        stageB<<<dim3(2 * NTILE), dim3(256), 0, stream>>>(x, sf, idx, wsW, wsH);
        tailCDE<<<dim3(NTILE), dim3(512), 0, stream>>>(wsW, wsH, out);
    } else {
        hyper_fb<<<dim3(NTILE), dim3(512), 0, stream>>>(
            x, sf, idx, W0, W1, G1, G2, GT, Wc, out);
    }
}